// Round 29
// baseline (458.355 us; speedup 1.0000x reference)
//
#include <hip/hip_runtime.h>

#define N_NODES 100000
#define N_PAD   100032   // 1563 * 64 -- padded node count for guard-free staging
#define N_EDGES 1600000
#define T_STEPS 6
#define FDIM    64
#define SEG     (T_STEPS * N_NODES)
#define C2      0.01f
#define PADF    68   // LDS row stride: 17 quads (272B); plane = 64*272B = 17408B
#define SCRP    68   // scr stash row stride (conflict-free pass-A reads, r28)
#define RFL __builtin_amdgcn_readfirstlane

// ===== VERBATIM r22 k_build (int2-packed edge data) =====
__global__ __launch_bounds__(256) void k_build(
    const int* __restrict__ src, const int* __restrict__ dst,
    const int* __restrict__ tix, int* __restrict__ head,
    int2* __restrict__ edat)
{
  const int e = blockIdx.x * blockDim.x + threadIdx.x;
  if (e >= N_EDGES) return;
  const int key = tix[e] * N_NODES + dst[e];
  const int prev = atomicExch(&head[key], e);
  edat[e] = make_int2(src[e], prev);
}

// r28 k_sum6s with the addend-select moved to the SCALAR pipe: dead chains
// gather from a 256B zeros row (pointer select = s_cselect, free) and the
// per-lane v_cndmask disappears -- v += f unconditionally, where f == 0.0f
// for dead chains, the EXACT addend the old branchless form selected ->
// bit-identical arithmetic. Halves the walk loop's per-lane VALU (r28:
// VALUBusy 71% was the binding pipe).
__global__ __launch_bounds__(256) void k_sum6s(
    const float* __restrict__ feat, const int2* __restrict__ edat,
    const int* __restrict__ head, const float* __restrict__ zrow,
    float* __restrict__ hsums)
{
  __shared__ float scr[4][T_STEPS * SCRP];   // 6.5KB: wave-private sum stash
  const int lane = threadIdx.x & 63;
  const int w = threadIdx.x >> 6;
  const int n = blockIdx.x * (blockDim.x >> 6) + w;
  if (n >= N_NODES) return;

  int e0 = RFL(head[(size_t)0 * N_NODES + n]);
  int e1 = RFL(head[(size_t)1 * N_NODES + n]);
  int e2 = RFL(head[(size_t)2 * N_NODES + n]);
  int e3 = RFL(head[(size_t)3 * N_NODES + n]);
  int e4 = RFL(head[(size_t)4 * N_NODES + n]);
  int e5 = RFL(head[(size_t)5 * N_NODES + n]);

  float v0 = 0.f, v1 = 0.f, v2 = 0.f, v3 = 0.f, v4 = 0.f, v5 = 0.f;
  int c0 = 0, c1 = 0, c2 = 0, c3 = 0, c4 = 0, c5 = 0;

  while ((e0 >= 0) | (e1 >= 0) | (e2 >= 0) | (e3 >= 0) | (e4 >= 0) | (e5 >= 0)) {
    const int a0 = e0 < 0 ? 0 : e0, a1 = e1 < 0 ? 0 : e1, a2 = e2 < 0 ? 0 : e2;
    const int a3 = e3 < 0 ? 0 : e3, a4 = e4 < 0 ? 0 : e4, a5 = e5 < 0 ? 0 : e5;

    const int2 d0 = edat[a0];
    const int2 d1 = edat[a1];
    const int2 d2 = edat[a2];
    const int2 d3 = edat[a3];
    const int2 d4 = edat[a4];
    const int2 d5 = edat[a5];

    const int s0 = RFL(d0.x), x0 = RFL(d0.y);
    const int s1 = RFL(d1.x), x1 = RFL(d1.y);
    const int s2 = RFL(d2.x), x2 = RFL(d2.y);
    const int s3 = RFL(d3.x), x3 = RFL(d3.y);
    const int s4 = RFL(d4.x), x4 = RFL(d4.y);
    const int s5 = RFL(d5.x), x5 = RFL(d5.y);

    // scalar pointer select: dead chain -> zeros row (f = 0.0f, the same
    // addend the old per-lane cndmask produced)
    const float* p0 = (e0 >= 0) ? (feat + (size_t)s0 * FDIM) : zrow;
    const float* p1 = (e1 >= 0) ? (feat + (size_t)s1 * FDIM) : zrow;
    const float* p2 = (e2 >= 0) ? (feat + (size_t)s2 * FDIM) : zrow;
    const float* p3 = (e3 >= 0) ? (feat + (size_t)s3 * FDIM) : zrow;
    const float* p4 = (e4 >= 0) ? (feat + (size_t)s4 * FDIM) : zrow;
    const float* p5 = (e5 >= 0) ? (feat + (size_t)s5 * FDIM) : zrow;

    const float f0 = p0[lane];
    const float f1 = p1[lane];
    const float f2 = p2[lane];
    const float f3 = p3[lane];
    const float f4 = p4[lane];
    const float f5 = p5[lane];

    v0 += f0;  c0 += (e0 >= 0);  e0 = (e0 >= 0) ? x0 : -1;
    v1 += f1;  c1 += (e1 >= 0);  e1 = (e1 >= 0) ? x1 : -1;
    v2 += f2;  c2 += (e2 >= 0);  e2 = (e2 >= 0) ? x2 : -1;
    v3 += f3;  c3 += (e3 >= 0);  e3 = (e3 >= 0) ? x3 : -1;
    v4 += f4;  c4 += (e4 >= 0);  e4 = (e4 >= 0) ? x4 : -1;
    v5 += f5;  c5 += (e5 >= 0);  e5 = (e5 >= 0) ? x5 : -1;
  }

  // stash raw sums (wave-private; stride SCRP=68 -> conflict-free reads)
  scr[w][0 * SCRP + lane] = v0;
  scr[w][1 * SCRP + lane] = v1;
  scr[w][2 * SCRP + lane] = v2;
  scr[w][3 * SCRP + lane] = v3;
  scr[w][4 * SCRP + lane] = v4;
  scr[w][5 * SCRP + lane] = v5;

  // ---- pass A, verbatim r1 expression tree, lane t handles plane t ----
  float sv = 0.0f;
  if (lane < T_STEPS) {
    const int ci = (lane == 0) ? c0 : (lane == 1) ? c1 : (lane == 2) ? c2
                 : (lane == 3) ? c3 : (lane == 4) ? c4 : c5;
    const float c  = (float)ci;
    const float rc = 1.0f / fmaxf(c, 1.0f);
    const float4* row = (const float4*)(&scr[w][lane * SCRP]);
    float ss = 0.0f;
    #pragma unroll
    for (int q = 0; q < FDIM / 4; ++q) {
      float4 v = row[q];
      float m0 = v.x * rc, m1 = v.y * rc, m2 = v.z * rc, m3 = v.w * rc;
      ss += m0 * m0 + m1 * m1 + m2 * m2 + m3 * m3;
    }
    const float norm = 1.0f - C2 * ss;
    sv = rc / norm;
  }
  const float sc0 = __shfl(sv, 0, 64);
  const float sc1 = __shfl(sv, 1, 64);
  const float sc2 = __shfl(sv, 2, 64);
  const float sc3 = __shfl(sv, 3, 64);
  const float sc4 = __shfl(sv, 4, 64);
  const float sc5 = __shfl(sv, 5, 64);

  // pre-scaled store: v*s == the gemm's old hs = hv[i]*s, bit-identical
  hsums[((size_t)0 * N_PAD + n) * FDIM + lane] = v0 * sc0;
  hsums[((size_t)1 * N_PAD + n) * FDIM + lane] = v1 * sc1;
  hsums[((size_t)2 * N_PAD + n) * FDIM + lane] = v2 * sc2;
  hsums[((size_t)3 * N_PAD + n) * FDIM + lane] = v3 * sc3;
  hsums[((size_t)4 * N_PAD + n) * FDIM + lane] = v4 * sc4;
  hsums[((size_t)5 * N_PAD + n) * FDIM + lane] = v5 * sc5;
}

// Direct global->LDS (no VGPR round trip). Lane-linear dest: wave writes
// 1KB at uniform base; lane l's 16B comes from its own global addr.
__device__ __forceinline__ void gl16(const float* g, float* l) {
  __builtin_amdgcn_global_load_lds(
      (const __attribute__((address_space(1))) void*)g,
      (__attribute__((address_space(3))) void*)l, 16, 0, 0);
}

// ===== VERBATIM r27 pipelined pass-B gemm =====
template <int OUTF, int JBLK>
__global__ __launch_bounds__(256) void k_gemm_pb(
    const float* __restrict__ hsums, const float* __restrict__ W,
    const float* __restrict__ bias, float* __restrict__ out)
{
  __shared__ float lds[2][64 * PADF];   // 2 plane buffers x 17408 B
  const int tid = threadIdx.x;
  const int lane = tid & 63;
  const int wv = RFL(tid >> 6);
  const int n0 = blockIdx.x * 64;
  const int jb = wv * JBLK;

  int n = n0 + lane;
  const bool valid = (n < N_NODES);
  if (!valid) n = N_NODES - 1;

  float acc[JBLK];
  #pragma unroll
  for (int j = 0; j < JBLK; ++j) acc[j] = bias[jb + j];

  #define STAGE_PL(B, T)                                                      \
    for (int c = wv; c < 17; c += 4) {                                        \
      const int p  = c * 64 + lane;                                           \
      const int u  = p / 17;                                                  \
      const int qq = (p % 17) & 15;                                           \
      gl16(hsums + ((size_t)(T) * N_PAD + n0 + u) * FDIM + qq * 4,            \
           &lds[B][0] + c * 256);                                             \
    }

  STAGE_PL(0, 0);
  __syncthreads();

  #pragma unroll 1
  for (int t = 0; t < T_STEPS; ++t) {
    const float4* row = (const float4*)(&lds[t & 1][lane * PADF]);
    if (t + 1 < T_STEPS) { STAGE_PL((t + 1) & 1, t + 1); }

    #pragma unroll
    for (int q8 = 0; q8 < FDIM / 8; ++q8) {
      const float4 a = row[q8 * 2 + 0];
      const float4 b4 = row[q8 * 2 + 1];
      const float hv[8] = {a.x, a.y, a.z, a.w, b4.x, b4.y, b4.z, b4.w};
      const float* wr = W + ((size_t)t * FDIM + q8 * 8) * OUTF + jb;
      #pragma unroll
      for (int i = 0; i < 8; ++i) {
        #pragma unroll
        for (int j = 0; j < JBLK; ++j)
          acc[j] = fmaf(hv[i], wr[i * OUTF + j], acc[j]);
      }
    }

    __syncthreads();   // drains prefetch vmcnt AFTER the fma block
  }
  #undef STAGE_PL

  if (valid) {
    float* o = out + (size_t)n * OUTF + jb;
    #pragma unroll
    for (int j = 0; j < JBLK; ++j) o[j] = fmaxf(acc[j], 0.0f);
  }
}

extern "C" void kernel_launch(void* const* d_in, const int* in_sizes, int n_in,
                              void* d_out, int out_size, void* d_ws, size_t ws_size,
                              hipStream_t stream) {
  const float* x  = (const float*)d_in[0];
  const int*  ei  = (const int*)d_in[1];
  const int*  tix = (const int*)d_in[2];
  const float* W1 = (const float*)d_in[3];
  const float* b1 = (const float*)d_in[4];
  const float* W2 = (const float*)d_in[5];
  const float* b2 = (const float*)d_in[6];

  const int* src = ei;
  const int* dst = ei + N_EDGES;

  // Workspace: zrow[64] (256B of zeros) | head[SEG] (2.4MB) | edat[NE] int2
  // (12.8MB) | hsums[6*N_PAD*64] | h1[N_PAD*64]. zrow+head+edat = 15.2MB+256B
  // (256B-multiple) -> hsums rows stay 256B-aligned (r21 lesson).
  float* zrow  = (float*)d_ws;
  int*   head  = (int*)(zrow + 64);
  int2*  edat  = (int2*)(head + SEG);
  float* hsums = (float*)(edat + N_EDGES);
  float* h1    = hsums + (size_t)T_STEPS * N_PAD * FDIM;

  const int sum_grid = (N_NODES + 3) / 4;        // k_sum6s: 4 waves/block
  const int ngrp     = (N_NODES + 63) / 64;      // 1563 64-node groups

  hipMemsetAsync(zrow, 0, 64 * sizeof(float), stream);
  hipMemsetAsync(head, 0xFF, (size_t)SEG * sizeof(int), stream);
  k_build<<<(N_EDGES + 255) / 256, 256, 0, stream>>>(src, dst, tix, head, edat);

  // Layer 1
  k_sum6s<<<sum_grid, 256, 0, stream>>>(x, edat, head, zrow, hsums);
  k_gemm_pb<64, 16><<<ngrp, 256, 0, stream>>>(hsums, W1, b1, h1);

  // Layer 2 (same edge lists)
  k_sum6s<<<sum_grid, 256, 0, stream>>>(h1, edat, head, zrow, hsums);
  k_gemm_pb<16, 4><<<ngrp, 256, 0, stream>>>(hsums, W2, b2, (float*)d_out);
}

// Round 30
// 419.098 us; speedup vs baseline: 1.0937x; 1.0937x over previous
//
#include <hip/hip_runtime.h>

#define N_NODES 100000
#define N_PAD   100032   // 1563 * 64 -- padded node count for guard-free staging
#define N_EDGES 1600000
#define T_STEPS 6
#define FDIM    64
#define SEG     (T_STEPS * N_NODES)
#define C2      0.01f
#define PADF    68   // LDS row stride: 17 quads (272B); plane = 64*272B = 17408B
#define SCRP    68   // scr stash row stride (conflict-free pass-A reads, r28)
#define RFL __builtin_amdgcn_readfirstlane

// ===== VERBATIM r22 k_build (int2-packed edge data) =====
__global__ __launch_bounds__(256) void k_build(
    const int* __restrict__ src, const int* __restrict__ dst,
    const int* __restrict__ tix, int* __restrict__ head,
    int2* __restrict__ edat)
{
  const int e = blockIdx.x * blockDim.x + threadIdx.x;
  if (e >= N_EDGES) return;
  const int key = tix[e] * N_NODES + dst[e];
  const int prev = atomicExch(&head[key], e);
  edat[e] = make_int2(src[e], prev);
}

// ===== VERBATIM r28 k_sum6s (champion): scalarized 6-chain walk + fused
// pass A + pre-scale, SCRP=68 conflict-free stash. r29's scalar pointer-
// select regressed (lengthened the gather-issue dependency chain). =====
__global__ __launch_bounds__(256) void k_sum6s(
    const float* __restrict__ feat, const int2* __restrict__ edat,
    const int* __restrict__ head, float* __restrict__ hsums)
{
  __shared__ float scr[4][T_STEPS * SCRP];   // 6.5KB: wave-private sum stash
  const int lane = threadIdx.x & 63;
  const int w = threadIdx.x >> 6;
  const int n = blockIdx.x * (blockDim.x >> 6) + w;
  if (n >= N_NODES) return;

  int e0 = RFL(head[(size_t)0 * N_NODES + n]);
  int e1 = RFL(head[(size_t)1 * N_NODES + n]);
  int e2 = RFL(head[(size_t)2 * N_NODES + n]);
  int e3 = RFL(head[(size_t)3 * N_NODES + n]);
  int e4 = RFL(head[(size_t)4 * N_NODES + n]);
  int e5 = RFL(head[(size_t)5 * N_NODES + n]);

  float v0 = 0.f, v1 = 0.f, v2 = 0.f, v3 = 0.f, v4 = 0.f, v5 = 0.f;
  int c0 = 0, c1 = 0, c2 = 0, c3 = 0, c4 = 0, c5 = 0;

  while ((e0 >= 0) | (e1 >= 0) | (e2 >= 0) | (e3 >= 0) | (e4 >= 0) | (e5 >= 0)) {
    const int a0 = e0 < 0 ? 0 : e0, a1 = e1 < 0 ? 0 : e1, a2 = e2 < 0 ? 0 : e2;
    const int a3 = e3 < 0 ? 0 : e3, a4 = e4 < 0 ? 0 : e4, a5 = e5 < 0 ? 0 : e5;

    const int2 d0 = edat[a0];
    const int2 d1 = edat[a1];
    const int2 d2 = edat[a2];
    const int2 d3 = edat[a3];
    const int2 d4 = edat[a4];
    const int2 d5 = edat[a5];

    const int s0 = RFL(d0.x), x0 = RFL(d0.y);
    const int s1 = RFL(d1.x), x1 = RFL(d1.y);
    const int s2 = RFL(d2.x), x2 = RFL(d2.y);
    const int s3 = RFL(d3.x), x3 = RFL(d3.y);
    const int s4 = RFL(d4.x), x4 = RFL(d4.y);
    const int s5 = RFL(d5.x), x5 = RFL(d5.y);

    const float f0 = feat[(size_t)s0 * FDIM + lane];
    const float f1 = feat[(size_t)s1 * FDIM + lane];
    const float f2 = feat[(size_t)s2 * FDIM + lane];
    const float f3 = feat[(size_t)s3 * FDIM + lane];
    const float f4 = feat[(size_t)s4 * FDIM + lane];
    const float f5 = feat[(size_t)s5 * FDIM + lane];

    v0 += (e0 >= 0) ? f0 : 0.0f;  c0 += (e0 >= 0);  e0 = (e0 >= 0) ? x0 : -1;
    v1 += (e1 >= 0) ? f1 : 0.0f;  c1 += (e1 >= 0);  e1 = (e1 >= 0) ? x1 : -1;
    v2 += (e2 >= 0) ? f2 : 0.0f;  c2 += (e2 >= 0);  e2 = (e2 >= 0) ? x2 : -1;
    v3 += (e3 >= 0) ? f3 : 0.0f;  c3 += (e3 >= 0);  e3 = (e3 >= 0) ? x3 : -1;
    v4 += (e4 >= 0) ? f4 : 0.0f;  c4 += (e4 >= 0);  e4 = (e4 >= 0) ? x4 : -1;
    v5 += (e5 >= 0) ? f5 : 0.0f;  c5 += (e5 >= 0);  e5 = (e5 >= 0) ? x5 : -1;
  }

  // stash raw sums (wave-private; stride SCRP=68 -> pass-A reads conflict-free)
  scr[w][0 * SCRP + lane] = v0;
  scr[w][1 * SCRP + lane] = v1;
  scr[w][2 * SCRP + lane] = v2;
  scr[w][3 * SCRP + lane] = v3;
  scr[w][4 * SCRP + lane] = v4;
  scr[w][5 * SCRP + lane] = v5;

  // ---- pass A, verbatim r1 expression tree, lane t handles plane t ----
  float sv = 0.0f;
  if (lane < T_STEPS) {
    const int ci = (lane == 0) ? c0 : (lane == 1) ? c1 : (lane == 2) ? c2
                 : (lane == 3) ? c3 : (lane == 4) ? c4 : c5;
    const float c  = (float)ci;
    const float rc = 1.0f / fmaxf(c, 1.0f);
    const float4* row = (const float4*)(&scr[w][lane * SCRP]);
    float ss = 0.0f;
    #pragma unroll
    for (int q = 0; q < FDIM / 4; ++q) {
      float4 v = row[q];
      float m0 = v.x * rc, m1 = v.y * rc, m2 = v.z * rc, m3 = v.w * rc;
      ss += m0 * m0 + m1 * m1 + m2 * m2 + m3 * m3;
    }
    const float norm = 1.0f - C2 * ss;
    sv = rc / norm;
  }
  const float sc0 = __shfl(sv, 0, 64);
  const float sc1 = __shfl(sv, 1, 64);
  const float sc2 = __shfl(sv, 2, 64);
  const float sc3 = __shfl(sv, 3, 64);
  const float sc4 = __shfl(sv, 4, 64);
  const float sc5 = __shfl(sv, 5, 64);

  // pre-scaled store: v*s == the gemm's old hs = hv[i]*s, bit-identical
  hsums[((size_t)0 * N_PAD + n) * FDIM + lane] = v0 * sc0;
  hsums[((size_t)1 * N_PAD + n) * FDIM + lane] = v1 * sc1;
  hsums[((size_t)2 * N_PAD + n) * FDIM + lane] = v2 * sc2;
  hsums[((size_t)3 * N_PAD + n) * FDIM + lane] = v3 * sc3;
  hsums[((size_t)4 * N_PAD + n) * FDIM + lane] = v4 * sc4;
  hsums[((size_t)5 * N_PAD + n) * FDIM + lane] = v5 * sc5;
}

// Direct global->LDS (no VGPR round trip). Lane-linear dest: wave writes
// 1KB at uniform base; lane l's 16B comes from its own global addr.
__device__ __forceinline__ void gl16(const float* g, float* l) {
  __builtin_amdgcn_global_load_lds(
      (const __attribute__((address_space(1))) void*)g,
      (__attribute__((address_space(3))) void*)l, 16, 0, 0);
}

// ===== VERBATIM r27 pipelined pass-B gemm =====
template <int OUTF, int JBLK>
__global__ __launch_bounds__(256) void k_gemm_pb(
    const float* __restrict__ hsums, const float* __restrict__ W,
    const float* __restrict__ bias, float* __restrict__ out)
{
  __shared__ float lds[2][64 * PADF];   // 2 plane buffers x 17408 B
  const int tid = threadIdx.x;
  const int lane = tid & 63;
  const int wv = RFL(tid >> 6);
  const int n0 = blockIdx.x * 64;
  const int jb = wv * JBLK;

  int n = n0 + lane;
  const bool valid = (n < N_NODES);
  if (!valid) n = N_NODES - 1;

  float acc[JBLK];
  #pragma unroll
  for (int j = 0; j < JBLK; ++j) acc[j] = bias[jb + j];

  #define STAGE_PL(B, T)                                                      \
    for (int c = wv; c < 17; c += 4) {                                        \
      const int p  = c * 64 + lane;                                           \
      const int u  = p / 17;                                                  \
      const int qq = (p % 17) & 15;                                           \
      gl16(hsums + ((size_t)(T) * N_PAD + n0 + u) * FDIM + qq * 4,            \
           &lds[B][0] + c * 256);                                             \
    }

  STAGE_PL(0, 0);
  __syncthreads();

  #pragma unroll 1
  for (int t = 0; t < T_STEPS; ++t) {
    const float4* row = (const float4*)(&lds[t & 1][lane * PADF]);
    if (t + 1 < T_STEPS) { STAGE_PL((t + 1) & 1, t + 1); }

    #pragma unroll
    for (int q8 = 0; q8 < FDIM / 8; ++q8) {
      const float4 a = row[q8 * 2 + 0];
      const float4 b4 = row[q8 * 2 + 1];
      const float hv[8] = {a.x, a.y, a.z, a.w, b4.x, b4.y, b4.z, b4.w};
      const float* wr = W + ((size_t)t * FDIM + q8 * 8) * OUTF + jb;
      #pragma unroll
      for (int i = 0; i < 8; ++i) {
        #pragma unroll
        for (int j = 0; j < JBLK; ++j)
          acc[j] = fmaf(hv[i], wr[i * OUTF + j], acc[j]);
      }
    }

    __syncthreads();   // drains prefetch vmcnt AFTER the fma block
  }
  #undef STAGE_PL

  if (valid) {
    float* o = out + (size_t)n * OUTF + jb;
    #pragma unroll
    for (int j = 0; j < JBLK; ++j) o[j] = fmaxf(acc[j], 0.0f);
  }
}

extern "C" void kernel_launch(void* const* d_in, const int* in_sizes, int n_in,
                              void* d_out, int out_size, void* d_ws, size_t ws_size,
                              hipStream_t stream) {
  const float* x  = (const float*)d_in[0];
  const int*  ei  = (const int*)d_in[1];
  const int*  tix = (const int*)d_in[2];
  const float* W1 = (const float*)d_in[3];
  const float* b1 = (const float*)d_in[4];
  const float* W2 = (const float*)d_in[5];
  const float* b2 = (const float*)d_in[6];

  const int* src = ei;
  const int* dst = ei + N_EDGES;

  // Workspace: head[SEG] (2.4MB) | edat[NE] int2 (12.8MB) | hsums[6*N_PAD*64]
  //          | h1[N_PAD*64]. head+edat = 15.2MB (256B-multiple) -> hsums rows
  // 256B-aligned (r21 lesson).
  int*   head  = (int*)d_ws;
  int2*  edat  = (int2*)(head + SEG);
  float* hsums = (float*)(edat + N_EDGES);
  float* h1    = hsums + (size_t)T_STEPS * N_PAD * FDIM;

  const int sum_grid = (N_NODES + 3) / 4;        // k_sum6s: 4 waves/block
  const int ngrp     = (N_NODES + 63) / 64;      // 1563 64-node groups

  hipMemsetAsync(head, 0xFF, (size_t)SEG * sizeof(int), stream);
  k_build<<<(N_EDGES + 255) / 256, 256, 0, stream>>>(src, dst, tix, head, edat);

  // Layer 1
  k_sum6s<<<sum_grid, 256, 0, stream>>>(x, edat, head, hsums);
  k_gemm_pb<64, 16><<<ngrp, 256, 0, stream>>>(hsums, W1, b1, h1);

  // Layer 2 (same edge lists)
  k_sum6s<<<sum_grid, 256, 0, stream>>>(h1, edat, head, hsums);
  k_gemm_pb<16, 4><<<ngrp, 256, 0, stream>>>(hsums, W2, b2, (float*)d_out);
}